// Round 1
// baseline (200.337 us; speedup 1.0000x reference)
//
#include <hip/hip_runtime.h>

#define NB 8732
#define NC 21
#define BATCH 128

__device__ inline float wred_f(float v) {
#pragma unroll
    for (int o = 32; o > 0; o >>= 1) v += __shfl_down(v, o, 64);
    return v;
}
__device__ inline int wred_i(int v) {
#pragma unroll
    for (int o = 32; o > 0; o >>= 1) v += __shfl_down(v, o, 64);
    return v;
}

// Per-box: CE (log-softmax at label) + smooth-L1 loc loss for positives.
// Accumulate per-row: sum(ce) over all boxes, sum(ce) over positives, count(pos).
// Accumulate global: loc loss.
__global__ void __launch_bounds__(256)
kA(const float* __restrict__ locp, const float* __restrict__ loct,
   const float* __restrict__ conf, const int* __restrict__ lab,
   float* __restrict__ row_ce, float* __restrict__ row_pce,
   int* __restrict__ row_np, float* __restrict__ loc_acc) {
    const int r = blockIdx.y;
    const int i = blockIdx.x * 256 + threadIdx.x;
    float ce = 0.f, pce = 0.f, ll = 0.f;
    int pc = 0;
    if (i < NB) {
        const long box = (long)r * NB + i;
        const int l = lab[box];
        const float* cp = conf + box * (long)NC;
        float c[NC];
#pragma unroll
        for (int j = 0; j < NC; j++) c[j] = cp[j];
        float m = c[0];
#pragma unroll
        for (int j = 1; j < NC; j++) m = fmaxf(m, c[j]);
        float s = 0.f;
#pragma unroll
        for (int j = 0; j < NC; j++) s += __expf(c[j] - m);
        const float lse = m + __logf(s);
        const float gold = cp[l];  // dynamic index -> direct load (L1 hit)
        ce = lse - gold;
        const bool pos = l > 0;

        const float4 lp = *(const float4*)(locp + box * 4);
        const float4 lt = *(const float4*)(loct + box * 4);
        float sl = 0.f, d, ad;
        d = lp.x - lt.x; ad = fabsf(d); sl += (ad < 1.f) ? 0.5f * d * d : ad - 0.5f;
        d = lp.y - lt.y; ad = fabsf(d); sl += (ad < 1.f) ? 0.5f * d * d : ad - 0.5f;
        d = lp.z - lt.z; ad = fabsf(d); sl += (ad < 1.f) ? 0.5f * d * d : ad - 0.5f;
        d = lp.w - lt.w; ad = fabsf(d); sl += (ad < 1.f) ? 0.5f * d * d : ad - 0.5f;
        if (pos) { pc = 1; pce = ce; ll = sl; }
    }

    __shared__ float sr[3][4];
    __shared__ int si[4];
    float v0 = wred_f(ce), v1 = wred_f(pce), v2 = wred_f(ll);
    int v3 = wred_i(pc);
    const int w = threadIdx.x >> 6, ln = threadIdx.x & 63;
    if (ln == 0) { sr[0][w] = v0; sr[1][w] = v1; sr[2][w] = v2; si[w] = v3; }
    __syncthreads();
    if (threadIdx.x == 0) {
        float A = 0, B = 0, C = 0; int D = 0;
#pragma unroll
        for (int k = 0; k < 4; k++) { A += sr[0][k]; B += sr[1][k]; C += sr[2][k]; D += si[k]; }
        atomicAdd(&row_ce[r], A);
        atomicAdd(&row_pce[r], B);
        atomicAdd(loc_acc, C);
        atomicAdd(&row_np[r], D);
    }
}

__device__ inline float ce_for_box(const float* __restrict__ cp) {
    // label == 0 path: gold = cp[0]
    float c[NC];
#pragma unroll
    for (int j = 0; j < NC; j++) c[j] = cp[j];
    float m = c[0];
#pragma unroll
    for (int j = 1; j < NC; j++) m = fmaxf(m, c[j]);
    float s = 0.f;
#pragma unroll
    for (int j = 0; j < NC; j++) s += __expf(c[j] - m);
    return m + __logf(s) - c[0];
}

// Per-row hard-negative mining + conf loss accumulation.
// Hot path (K >= #negatives): sel = all boxes -> conf_row = row_ce (no sort!).
// Cold path: radix-select the K-th largest negative ce; ties at the threshold
// have identical ce so (K-G)*val(t) is exact regardless of index tie-break.
__global__ void __launch_bounds__(256)
kB(const float* __restrict__ conf, const int* __restrict__ lab,
   const float* __restrict__ row_ce, const float* __restrict__ row_pce,
   const int* __restrict__ row_np, float* __restrict__ conf_acc) {
    const int r = blockIdx.x;
    const int np = row_np[r];
    const int K = min(3 * np, NB - 1);
    const int nneg = NB - np;

    if (K >= nneg) {
        if (threadIdx.x == 0) atomicAdd(conf_acc, row_ce[r]);
        return;
    }
    if (K <= 0) {
        if (threadIdx.x == 0) atomicAdd(conf_acc, row_pce[r]);
        return;
    }

    // ---- cold path: top-K among negatives via 4-round radix select ----
    __shared__ unsigned key[NB];
    __shared__ unsigned hist[256];
    __shared__ unsigned sb[2];

    for (int i = threadIdx.x; i < NB; i += 256) {
        const long box = (long)r * NB + i;
        unsigned k = 0u;  // positives: sentinel 0 (never > any threshold >= 0)
        if (lab[box] == 0) {
            float ce = ce_for_box(conf + box * (long)NC);
            k = __float_as_uint(fmaxf(ce, 0.f));  // ce>=0 -> bits are order-preserving
        }
        key[i] = k;
    }
    __syncthreads();

    unsigned prefix = 0;
    int Kr = K;
    for (int round = 3; round >= 0; --round) {
        const int sh = round * 8;
        const unsigned pmask = (round == 3) ? 0u : (0xFFFFFFFFu << (8 * (round + 1)));
        for (int b = threadIdx.x; b < 256; b += 256) hist[b] = 0;
        __syncthreads();
        for (int i = threadIdx.x; i < NB; i += 256) {
            const unsigned k = key[i];
            if ((k & pmask) == prefix) atomicAdd(&hist[(k >> sh) & 255u], 1u);
        }
        __syncthreads();
        if (threadIdx.x == 0) {
            unsigned cum = 0; int b = 255;
            for (; b > 0; --b) {
                const unsigned h = hist[b];
                if (cum + h >= (unsigned)Kr) break;
                cum += h;
            }
            sb[0] = cum; sb[1] = (unsigned)b;
        }
        __syncthreads();
        const unsigned cum = sb[0];
        const int b = (int)sb[1];
        Kr -= (int)cum;
        prefix |= ((unsigned)b << sh);
        __syncthreads();
    }

    // sum of negatives with key > prefix, plus Kr copies of the threshold value
    float local = 0.f;
    for (int i = threadIdx.x; i < NB; i += 256) {
        const unsigned k = key[i];
        if (k > prefix) local += __uint_as_float(k);
    }
    __shared__ float sred[4];
    float v = wred_f(local);
    const int w = threadIdx.x >> 6, ln = threadIdx.x & 63;
    if (ln == 0) sred[w] = v;
    __syncthreads();
    if (threadIdx.x == 0) {
        float tot = sred[0] + sred[1] + sred[2] + sred[3];
        tot += (float)Kr * __uint_as_float(prefix);
        atomicAdd(conf_acc, row_pce[r] + tot);
    }
}

__global__ void kC(const float* __restrict__ loc_acc, const float* __restrict__ conf_acc,
                   const int* __restrict__ row_np, float* __restrict__ out) {
    if (threadIdx.x == 0 && blockIdx.x == 0) {
        int nm = 0;
        for (int r = 0; r < BATCH; r++) nm += row_np[r];
        const float denom = fmaxf((float)nm, 1.f);
        out[0] = (loc_acc[0] + conf_acc[0]) / denom;
    }
}

extern "C" void kernel_launch(void* const* d_in, const int* in_sizes, int n_in,
                              void* d_out, int out_size, void* d_ws, size_t ws_size,
                              hipStream_t stream) {
    const float* locp = (const float*)d_in[0];
    const float* loct = (const float*)d_in[1];
    const float* conf = (const float*)d_in[2];
    const int* lab = (const int*)d_in[3];
    float* out = (float*)d_out;

    // ws layout (all < 4 KiB): [0]=loc_acc, [1]=conf_acc, [16..]=row_ce[128],
    // then row_pce[128], then row_np[128]
    float* loc_acc = (float*)d_ws;
    float* conf_acc = loc_acc + 1;
    float* row_ce = (float*)d_ws + 16;
    float* row_pce = row_ce + BATCH;
    int* row_np = (int*)(row_pce + BATCH);

    hipMemsetAsync(d_ws, 0, 4096, stream);

    dim3 gA((NB + 255) / 256, BATCH);
    hipLaunchKernelGGL(kA, gA, dim3(256), 0, stream,
                       locp, loct, conf, lab, row_ce, row_pce, row_np, loc_acc);
    hipLaunchKernelGGL(kB, dim3(BATCH), dim3(256), 0, stream,
                       conf, lab, row_ce, row_pce, row_np, conf_acc);
    hipLaunchKernelGGL(kC, dim3(1), dim3(1), 0, stream,
                       loc_acc, conf_acc, row_np, out);
}